// Round 1
// baseline (201.658 us; speedup 1.0000x reference)
//
#include <hip/hip_runtime.h>
#include <math.h>

#define BB 8
#define NN 2048
#define FF 128
#define CH 128        // chunks per batch
#define CHSZ 16       // NN / CH

// ---------------------------------------------------------------------------
// Kernel 1: Wh[b,n,g] = sum_f h[b,n,f] * W[g,f];  s1 = Wh·a[:F], s2 = Wh·a[F:]
// block = 512 threads, 64 rows/block, per-thread tile 8g x 2r.
// W staged transposed in LDS in two 64-f halves (stay < 64KB static LDS).
// ---------------------------------------------------------------------------
__global__ __launch_bounds__(512) void k1_wh(
        const float* __restrict__ h, const float* __restrict__ W,
        const float* __restrict__ a, float* __restrict__ Wh,
        float* __restrict__ s1, float* __restrict__ s2) {
    __shared__ __align__(16) float Wt[64][132];  // Wt[f_local][g], padded
    __shared__ float hs[64][65];                 // hs[r][f_local], padded
    const int tid = threadIdx.x;
    const int row0 = blockIdx.x * 64;            // global row = b*NN + i
    const int gq = tid & 15;                     // g = gq*8 .. gq*8+7
    const int rq = tid >> 4;                     // rows rq*2, rq*2+1

    float acc[2][8];
#pragma unroll
    for (int r = 0; r < 2; ++r)
#pragma unroll
        for (int g = 0; g < 8; ++g) acc[r][g] = 0.f;

    for (int half = 0; half < 2; ++half) {
        __syncthreads();
        // load W[g][half*64 + fl] -> Wt[fl][g]   (coalesced global read)
        for (int idx = tid; idx < 64 * 128; idx += 512) {
            int g = idx >> 6, fl = idx & 63;
            Wt[fl][g] = W[g * 128 + half * 64 + fl];
        }
        // load h rows -> hs[r][fl]
        for (int idx = tid; idx < 64 * 64; idx += 512) {
            int r = idx >> 6, fl = idx & 63;
            hs[r][fl] = h[(row0 + r) * 128 + half * 64 + fl];
        }
        __syncthreads();
        for (int fl = 0; fl < 64; ++fl) {
            float4 w0 = *(const float4*)&Wt[fl][gq * 8];
            float4 w1 = *(const float4*)&Wt[fl][gq * 8 + 4];
            float h0 = hs[rq * 2 + 0][fl];
            float h1 = hs[rq * 2 + 1][fl];
            acc[0][0] += h0 * w0.x; acc[0][1] += h0 * w0.y;
            acc[0][2] += h0 * w0.z; acc[0][3] += h0 * w0.w;
            acc[0][4] += h0 * w1.x; acc[0][5] += h0 * w1.y;
            acc[0][6] += h0 * w1.z; acc[0][7] += h0 * w1.w;
            acc[1][0] += h1 * w0.x; acc[1][1] += h1 * w0.y;
            acc[1][2] += h1 * w0.z; acc[1][3] += h1 * w0.w;
            acc[1][4] += h1 * w1.x; acc[1][5] += h1 * w1.y;
            acc[1][6] += h1 * w1.z; acc[1][7] += h1 * w1.w;
        }
    }

    float a1v[8], a2v[8];
#pragma unroll
    for (int g = 0; g < 8; ++g) {
        a1v[g] = a[gq * 8 + g];
        a2v[g] = a[128 + gq * 8 + g];
    }
#pragma unroll
    for (int r = 0; r < 2; ++r) {
        int row = row0 + rq * 2 + r;
        *(float4*)&Wh[row * 128 + gq * 8] =
            make_float4(acc[r][0], acc[r][1], acc[r][2], acc[r][3]);
        *(float4*)&Wh[row * 128 + gq * 8 + 4] =
            make_float4(acc[r][4], acc[r][5], acc[r][6], acc[r][7]);
        float p1 = 0.f, p2 = 0.f;
#pragma unroll
        for (int g = 0; g < 8; ++g) {
            p1 += acc[r][g] * a1v[g];
            p2 += acc[r][g] * a2v[g];
        }
        // reduce over the 16 gq lanes (low 4 lane bits)
#pragma unroll
        for (int s = 1; s < 16; s <<= 1) {
            p1 += __shfl_xor(p1, s, 64);
            p2 += __shfl_xor(p2, s, 64);
        }
        if (gq == 0) { s1[row] = p1; s2[row] = p2; }
    }
}

// ---------------------------------------------------------------------------
// Kernel 2: per-batch bitonic sort of (s2, idx) ascending; p = exp(s2s - M);
// suffix_exp[r] = sum_{r'>=r} p[r'].  One block (1024 thr) per batch.
// ---------------------------------------------------------------------------
__global__ __launch_bounds__(1024) void k2_sort(
        const float* __restrict__ s2, float* __restrict__ s2s,
        int* __restrict__ idxs, float* __restrict__ ps,
        float* __restrict__ sufexp) {
    __shared__ float sk[2048];
    __shared__ int   si[2048];
    __shared__ float scanA[1024];
    const int t = threadIdx.x;
    const int b = blockIdx.x;
    const int base = b * NN;

    sk[t] = s2[base + t];            si[t] = t;
    sk[t + 1024] = s2[base + t + 1024]; si[t + 1024] = t + 1024;

    for (int k = 2; k <= 2048; k <<= 1) {
        for (int j = k >> 1; j > 0; j >>= 1) {
            __syncthreads();
            int i = ((t & ~(j - 1)) << 1) | (t & (j - 1));
            int l = i | j;
            float va = sk[i], vb = sk[l];
            bool asc = ((i & k) == 0);
            bool sw = asc ? (va > vb) : (va < vb);
            if (sw) {
                int ia = si[i], ib = si[l];
                sk[i] = vb; sk[l] = va;
                si[i] = ib; si[l] = ia;
            }
        }
    }
    __syncthreads();
    float M = sk[2047];
    float p0 = expf(sk[2 * t] - M);
    float p1 = expf(sk[2 * t + 1] - M);
    scanA[t] = p0 + p1;
    __syncthreads();
    for (int s = 1; s < 1024; s <<= 1) {
        float add = (t + s < 1024) ? scanA[t + s] : 0.f;
        __syncthreads();
        scanA[t] += add;
        __syncthreads();
    }
    float excl = (t < 1023) ? scanA[t + 1] : 0.f;   // suffix excluding my pair
    s2s[base + 2 * t] = sk[2 * t];
    s2s[base + 2 * t + 1] = sk[2 * t + 1];
    idxs[base + 2 * t] = si[2 * t];
    idxs[base + 2 * t + 1] = si[2 * t + 1];
    ps[base + 2 * t] = p0;
    ps[base + 2 * t + 1] = p1;
    sufexp[base + 2 * t] = excl + p1 + p0;
    sufexp[base + 2 * t + 1] = excl + p1;
}

// ---------------------------------------------------------------------------
// Kernel 3: within-chunk inclusive suffix of p[r]*Wh[idx[r],:] (and unweighted
// sums for the mean).  grid = B*CH blocks, 128 threads (f).
// ---------------------------------------------------------------------------
__global__ __launch_bounds__(128) void k3_scan(
        const float* __restrict__ Wh, const float* __restrict__ s2s,
        const int* __restrict__ idxs, const float* __restrict__ ps,
        float* __restrict__ partial, float* __restrict__ chunktot,
        float* __restrict__ chunku) {
    const int blk = blockIdx.x;
    const int b = blk / CH, c = blk % CH;
    const int base = b * NN;
    const int f = threadIdx.x;
    float acc = 0.f, accu = 0.f;
#pragma unroll
    for (int tt = CHSZ - 1; tt >= 0; --tt) {
        int r = c * CHSZ + tt;
        int j = idxs[base + r];
        float pv = ps[base + r];
        float w = Wh[(base + j) * 128 + f];
        acc += pv * w;
        accu += w;
        partial[(base + r) * 128 + f] = acc;
    }
    chunktot[(b * CH + c) * 128 + f] = acc;
    chunku[(b * CH + c) * 128 + f] = accu;
    (void)s2s;
}

// ---------------------------------------------------------------------------
// Kernel 3b: exclusive suffix over chunk totals; mean over all j.
// ---------------------------------------------------------------------------
__global__ __launch_bounds__(128) void k3b_chunksuf(
        const float* __restrict__ chunktot, const float* __restrict__ chunku,
        float* __restrict__ chunksuf, float* __restrict__ meanv) {
    const int b = blockIdx.x;
    const int f = threadIdx.x;
    float acc = 0.f, tu = 0.f;
    for (int c = CH - 1; c >= 0; --c) {
        chunksuf[(b * CH + c) * 128 + f] = acc;
        acc += chunktot[(b * CH + c) * 128 + f];
        tu += chunku[(b * CH + c) * 128 + f];
    }
    meanv[b * 128 + f] = tu * (1.f / (float)NN);
}

// ---------------------------------------------------------------------------
// Kernel 4: per row binary search for threshold rank, combine, ELU.
// block = 256 threads -> 2 rows x 128 f.  grid = B*NN/2.
// ---------------------------------------------------------------------------
__global__ __launch_bounds__(256) void k4_out(
        const float* __restrict__ s1, const float* __restrict__ s2s,
        const float* __restrict__ sufexp, const float* __restrict__ partial,
        const float* __restrict__ chunksuf, const float* __restrict__ meanv,
        float* __restrict__ out) {
    const int tid = threadIdx.x;
    const int rowg = blockIdx.x * 2 + (tid >> 7);
    const int f = tid & 127;
    const int b = rowg >> 11;           // / NN
    const int base = b * NN;
    const float s1v = s1[rowg];
    int lo = 0, hi = NN;
    while (lo < hi) {                    // exact fp32 predicate == reference
        int mid = (lo + hi) >> 1;
        if (s1v + s2s[base + mid] > 0.f) hi = mid; else lo = mid + 1;
    }
    float v;
    if (lo == NN) {
        v = meanv[b * 128 + f];          // all masked -> uniform softmax
    } else {
        int c = lo >> 4;                 // / CHSZ
        float num = partial[(base + lo) * 128 + f] +
                    chunksuf[(b * CH + c) * 128 + f];
        v = num / sufexp[base + lo];
    }
    out[rowg * 128 + f] = (v > 0.f) ? v : expm1f(v);
}

// ---------------------------------------------------------------------------
extern "C" void kernel_launch(void* const* d_in, const int* in_sizes, int n_in,
                              void* d_out, int out_size, void* d_ws, size_t ws_size,
                              hipStream_t stream) {
    (void)in_sizes; (void)n_in; (void)out_size; (void)ws_size;
    const float* h = (const float*)d_in[0];
    const float* W = (const float*)d_in[1];
    const float* a = (const float*)d_in[2];
    // d_in[3]=A1, d_in[4]=A2: dead code in the reference -> never read.
    float* out = (float*)d_out;

    float* Wh      = (float*)d_ws;           // B*N*F      = 2,097,152
    float* partial = Wh + 2097152;           // B*N*F      = 2,097,152
    float* s1      = partial + 2097152;      // 16384
    float* s2      = s1 + 16384;
    float* s2s     = s2 + 16384;
    float* sufexp  = s2s + 16384;
    float* ps      = sufexp + 16384;
    int*   idxs    = (int*)(ps + 16384);     // 16384 ints
    float* chunktot = (float*)(idxs + 16384); // B*CH*F = 131072
    float* chunku   = chunktot + 131072;
    float* chunksuf = chunku + 131072;
    float* meanv    = chunksuf + 131072;     // 1024

    k1_wh<<<BB * NN / 64, 512, 0, stream>>>(h, W, a, Wh, s1, s2);
    k2_sort<<<BB, 1024, 0, stream>>>(s2, s2s, idxs, ps, sufexp);
    k3_scan<<<BB * CH, 128, 0, stream>>>(Wh, s2s, idxs, ps, partial, chunktot, chunku);
    k3b_chunksuf<<<BB, 128, 0, stream>>>(chunktot, chunku, chunksuf, meanv);
    k4_out<<<BB * NN / 2, 256, 0, stream>>>(s1, s2s, sufexp, partial, chunksuf, meanv, out);
}